// Round 9
// baseline (16.320 us; speedup 1.0000x reference)
//
#include <hip/hip_runtime.h>
#include <hip/hip_bf16.h>

// Fully-fused quantum photonic classifier via polynomial-coefficient DP.
// perm(B[rows mu]) / prod(mu!) = coeff of x^mu in prod_c (sum_m x_m B[m][c]).
// One block per sample (256 x 1024). DP stages 1(10)->2(55)->3(220)->4(715)->5.
// R9 vs R8: B1 + stage-2 + stage-3 run wave-synchronously on wave 0 only
// (single-wave DS ops are in-order; lgkmcnt fence instead of __syncthreads),
// cutting 12 block barriers to 8; waves 1-15 build e4/e5 edges in that gap.
// Phase-1 matvec gets 4-way ILP; mask1/Wout loads hoisted to kernel start.

__device__ __forceinline__ float2 cxmul(float2 a, float2 b) {
    float2 r;
    r.x = fmaf(a.x, b.x, -(a.y * b.y));
    r.y = fmaf(a.x, b.y, a.y * b.x);
    return r;
}

// exact C(c,k) for 0 <= c <= 14, 0 <= k <= 5. Products auto-zero for c < k.
__device__ __forceinline__ int Crt(int c, int k) {
    switch (k) {
        case 0:  return 1;
        case 1:  return c;
        case 2:  return (int)((unsigned)(c * (c - 1)) >> 1);
        case 3:  return (int)((unsigned)(c * (c - 1) * (c - 2)) / 6u);
        case 4:  return (int)((unsigned)(c * (c - 1) * (c - 2) * (c - 3)) / 24u);
        default: return (int)((unsigned)(c * (c - 1) * (c - 2) * (c - 3) * (c - 4)) / 120u);
    }
}

// colex unrank of a degree-D multiset over modes 0..9 (branchless).
template<int D>
__device__ __forceinline__ void unrank_ms(int R, int (&m)[D]) {
#pragma unroll
    for (int i = D - 1; i >= 0; --i) {
        int c = i;
#pragma unroll
        for (int v = 1; v <= 9; ++v)
            c += (Crt(i + v, i + 1) <= R) ? 1 : 0;
        R -= Crt(c, i + 1);
        m[i] = c - i;
    }
}

// For sorted multiset m[0..D-1]: edge j = (rank of multiset minus m[j],
// mode m[j]), valid only at first occurrence of each distinct value.
template<int D>
__device__ __forceinline__ void build_edges(const int (&m)[D], unsigned (&e)[D]) {
    int c[D];
#pragma unroll
    for (int i = 0; i < D; ++i) c[i] = m[i] + i;
    int P[D];
    P[0] = 0;
#pragma unroll
    for (int j = 1; j < D; ++j) P[j] = P[j - 1] + Crt(c[j - 1], j);
    int S[D];
    S[D - 1] = 0;
#pragma unroll
    for (int j = D - 2; j >= 0; --j) S[j] = S[j + 1] + Crt(c[j + 1] - 1, j + 1);
#pragma unroll
    for (int j = 0; j < D; ++j) {
        bool valid = (j == 0) || (m[j] != m[j - 1]);
        unsigned edge = (((unsigned)(P[j] + S[j])) << 4) | (unsigned)m[j] | 0x80000000u;
        e[j] = valid ? edge : 0u;
    }
}

// acc += B[mode][col] * parent_coeff   (complex, 4 fma)
__device__ __forceinline__ float2 dp_acc(float2 acc, unsigned e, const float2* pbuf,
                                         const float2* B, int col) {
    if (e & 0x80000000u) {
        float2 p = pbuf[(e >> 4) & 0x3FFu];
        float2 b = B[(e & 15u) * 5 + col];
        acc.x = fmaf(b.x, p.x, acc.x);
        acc.x = fmaf(-b.y, p.y, acc.x);
        acc.y = fmaf(b.x, p.y, acc.y);
        acc.y = fmaf(b.y, p.x, acc.y);
    }
    return acc;
}

__global__ __launch_bounds__(1024) void k_fused(
    const float* __restrict__ x, const float* __restrict__ Wd, const float* __restrict__ bd,
    const float* __restrict__ U1L, const float* __restrict__ U1R,
    const float* __restrict__ UfL, const float* __restrict__ UfR,
    const float* __restrict__ Wout, const float* __restrict__ bout,
    const float* __restrict__ mask1, const float* __restrict__ norm2,
    const int* __restrict__ rows1, const int* __restrict__ rows2,
    float* __restrict__ out)
{
    const int n    = blockIdx.x;
    const int tid  = threadIdx.x;
    const int lane = tid & 63;
    const int wid  = tid >> 6;   // 16 waves

    __shared__ float2 Bsh[50];        // current circuit matrix (10 modes x 5 cols)
    __shared__ float2 buf1[220];      // DP stages 1,3
    __shared__ float2 buf2[715];      // DP stages 2,4
    __shared__ float  p1s[252];
    __shared__ float2 Dsh[10];
    __shared__ float  fred[16][2];

    // ---- early-issue global loads ---------------------------------------
    int m5a[5];
#pragma unroll
    for (int j = 0; j < 5; ++j) m5a[j] = 0;
    if (tid < 252) {
#pragma unroll
        for (int j = 0; j < 5; ++j) m5a[j] = rows1[tid * 5 + j];
    }
    int m5b0[5];                       // p0 = tid (< 2002 always)
#pragma unroll
    for (int j = 0; j < 5; ++j) m5b0[j] = rows2[tid * 5 + j];
    int m5b1[5];                       // p1 = tid + 1024
#pragma unroll
    for (int j = 0; j < 5; ++j) m5b1[j] = 0;
    const bool has_p1 = (tid + 1024) < 2002;
    if (has_p1) {
#pragma unroll
        for (int j = 0; j < 5; ++j) m5b1[j] = rows2[(tid + 1024) * 5 + j];
    }
    // W_out hoists (used at the very end)
    const float w0a = Wout[tid];
    const float w1a = Wout[2002 + tid];
    const float w0b = has_p1 ? Wout[tid + 1024] : 0.f;
    const float w1b = has_p1 ? Wout[2002 + tid + 1024] : 0.f;
    // mask1 hoist for the e1 reduce (wave wid handles mode wid)
    float mk[4];
#pragma unroll
    for (int t = 0; t < 4; ++t) mk[t] = 0.f;
    if (wid < 10) {
#pragma unroll
        for (int t = 0; t < 4; ++t) {
            const int p = lane + t * 64;
            mk[t] = (p < 252) ? mask1[p * 10 + wid] : 0.f;
        }
    }

    // ---- phase 1: wave j computes h[j] = x[n]·Wd[j,:] + bd[j] -> D1 -----
    if (wid < 10) {
        const float* xr = x + n * 784;
        const float* wr = Wd + wid * 784;
        float s0 = 0.f, s1 = 0.f, s2 = 0.f, s3 = 0.f;
#pragma unroll
        for (int t = 0; t < 12; t += 4) {
            s0 = fmaf(xr[lane + t * 64],       wr[lane + t * 64],       s0);
            s1 = fmaf(xr[lane + (t + 1) * 64], wr[lane + (t + 1) * 64], s1);
            s2 = fmaf(xr[lane + (t + 2) * 64], wr[lane + (t + 2) * 64], s2);
            s3 = fmaf(xr[lane + (t + 3) * 64], wr[lane + (t + 3) * 64], s3);
        }
        if (lane < 16) s0 = fmaf(xr[lane + 768], wr[lane + 768], s0);
        float s = (s0 + s1) + (s2 + s3);
#pragma unroll
        for (int off = 32; off > 0; off >>= 1) s += __shfl_xor(s, off, 64);
        if (lane == 0) {
            float h = s + bd[wid];
            float sn, cs;
            __sincosf(h * 0.31830988618379067154f, &sn, &cs);   // h / pi
            Dsh[wid] = make_float2(cs, sn);
        }
    }
    // stage-2 edges (wave 0 only uses them)
    unsigned e2[2];
#pragma unroll
    for (int j = 0; j < 2; ++j) e2[j] = 0u;
    if (tid < 55)  { int m[2]; unrank_ms<2>(tid, m); build_edges<2>(m, e2); }
    __syncthreads();                                            // [1] Dsh ready

    // ---- wave 0: B1 -> stage-2 -> stage-3 (wave-synchronous, no barriers)
    if (wid == 0) {
        if (lane < 50) {
            const int i = lane / 5, cc = lane % 5, k = 2 * cc;
            float2 a = make_float2(0.f, 0.f);
#pragma unroll
            for (int j = 0; j < 10; ++j) {
                float2 ul = make_float2(U1L[(i * 10 + j) * 2], U1L[(i * 10 + j) * 2 + 1]);
                float2 ur = make_float2(U1R[(j * 10 + k) * 2], U1R[(j * 10 + k) * 2 + 1]);
                float2 t = cxmul(cxmul(ul, Dsh[j]), ur);
                a.x += t.x; a.y += t.y;
            }
            Bsh[lane] = a;
            if (cc == 0) buf1[i] = a;      // stage-1 coeffs = B[:,0]
        }
        asm volatile("s_waitcnt lgkmcnt(0)" ::: "memory");
        __builtin_amdgcn_wave_barrier();
        if (lane < 55) {
            float2 a = make_float2(0.f, 0.f);
#pragma unroll
            for (int j = 0; j < 2; ++j) a = dp_acc(a, e2[j], buf1, Bsh, 1);
            buf2[lane] = a;
        }
        asm volatile("s_waitcnt lgkmcnt(0)" ::: "memory");
        __builtin_amdgcn_wave_barrier();
#pragma unroll
        for (int kk = 0; kk < 4; ++kk) {
            const int o = lane + kk * 64;
            if (o < 220) {
                int m[3]; unrank_ms<3>(o, m);
                unsigned e3t[3]; build_edges<3>(m, e3t);
                float2 a = make_float2(0.f, 0.f);
#pragma unroll
                for (int j = 0; j < 3; ++j) a = dp_acc(a, e3t[j], buf2, Bsh, 2);
                buf1[o] = a;
            }
        }
    }
    // waves 1-15 (and wave 0 after) build stage-4/5 edges in this gap
    unsigned e4[4];
#pragma unroll
    for (int j = 0; j < 4; ++j) e4[j] = 0u;
    if (tid < 715) { int m[4]; unrank_ms<4>(tid, m); build_edges<4>(m, e4); }
    unsigned e5a[5], e5b0[5], e5b1[5];
#pragma unroll
    for (int j = 0; j < 5; ++j) { e5a[j] = 0u; e5b1[j] = 0u; }
    if (tid < 252) { build_edges<5>(m5a, e5a); }
    build_edges<5>(m5b0, e5b0);
    if (has_p1) { build_edges<5>(m5b1, e5b1); }
    float fact0, fact1;
    {
        int f = 1, c = 1;
#pragma unroll
        for (int j = 1; j < 5; ++j) { c = (m5b0[j] == m5b0[j - 1]) ? c + 1 : 1; f *= c; }
        fact0 = (float)f;
        f = 1; c = 1;
#pragma unroll
        for (int j = 1; j < 5; ++j) { c = (m5b1[j] == m5b1[j - 1]) ? c + 1 : 1; f *= c; }
        fact1 = (float)f;
    }
    __syncthreads();                                            // [2] st3 ready

    // ---- circuit-1 stage 4 + 5 ------------------------------------------
    if (tid < 715) {
        float2 a = make_float2(0.f, 0.f);
#pragma unroll
        for (int j = 0; j < 4; ++j) a = dp_acc(a, e4[j], buf1, Bsh, 3);
        buf2[tid] = a;
    }
    __syncthreads();                                            // [3] st4 ready
    if (tid < 252) {
        float2 a = make_float2(0.f, 0.f);
#pragma unroll
        for (int j = 0; j < 5; ++j) a = dp_acc(a, e5a[j], buf2, Bsh, 4);
        p1s[tid] = fmaf(a.x, a.x, a.y * a.y);   // squarefree: prod(mu!) = 1
    }
    __syncthreads();                                            // [4] p1 ready

    // ---- e1: wave j computes (p1·mask1[:,j]) / sum(p1) -> D2 ------------
    if (wid < 10) {
        float sm = 0.f, st = 0.f;
#pragma unroll
        for (int t = 0; t < 4; ++t) {
            const int p = lane + t * 64;
            if (p < 252) {
                const float pv = p1s[p];
                sm = fmaf(pv, mk[t], sm);
                st += pv;
            }
        }
#pragma unroll
        for (int off = 32; off > 0; off >>= 1) {
            sm += __shfl_xor(sm, off, 64);
            st += __shfl_xor(st, off, 64);
        }
        if (lane == 0) {
            float e = sm / st;
            float sn, cs;
            __sincosf(e, &sn, &cs);
            Dsh[wid] = make_float2(cs, sn);
        }
    }
    __syncthreads();                                            // [5] D2 ready

    // ---- wave 0: B2 -> stage-2 -> stage-3 (wave-synchronous) ------------
    if (wid == 0) {
        if (lane < 50) {
            const int i = lane / 5, cc = lane % 5, k = 2 * cc;
            float2 a = make_float2(0.f, 0.f);
#pragma unroll
            for (int j = 0; j < 10; ++j) {
                float2 ul = make_float2(UfL[(i * 10 + j) * 2], UfL[(i * 10 + j) * 2 + 1]);
                float2 ur = make_float2(UfR[(j * 10 + k) * 2], UfR[(j * 10 + k) * 2 + 1]);
                float2 t = cxmul(cxmul(ul, Dsh[j]), ur);
                a.x += t.x; a.y += t.y;
            }
            Bsh[lane] = a;
            if (cc == 0) buf1[i] = a;
        }
        asm volatile("s_waitcnt lgkmcnt(0)" ::: "memory");
        __builtin_amdgcn_wave_barrier();
        if (lane < 55) {
            float2 a = make_float2(0.f, 0.f);
#pragma unroll
            for (int j = 0; j < 2; ++j) a = dp_acc(a, e2[j], buf1, Bsh, 1);
            buf2[lane] = a;
        }
        asm volatile("s_waitcnt lgkmcnt(0)" ::: "memory");
        __builtin_amdgcn_wave_barrier();
#pragma unroll
        for (int kk = 0; kk < 4; ++kk) {
            const int o = lane + kk * 64;
            if (o < 220) {
                int m[3]; unrank_ms<3>(o, m);
                unsigned e3t[3]; build_edges<3>(m, e3t);
                float2 a = make_float2(0.f, 0.f);
#pragma unroll
                for (int j = 0; j < 3; ++j) a = dp_acc(a, e3t[j], buf2, Bsh, 2);
                buf1[o] = a;
            }
        }
    }
    __syncthreads();                                            // [6] st3 ready

    // ---- circuit-2 stage 4 + 5 + W_out dot ------------------------------
    if (tid < 715) {
        float2 a = make_float2(0.f, 0.f);
#pragma unroll
        for (int j = 0; j < 4; ++j) a = dp_acc(a, e4[j], buf1, Bsh, 3);
        buf2[tid] = a;
    }
    __syncthreads();                                            // [7] st4 ready
    float f0 = 0.f, f1 = 0.f;
    {
        float2 a = make_float2(0.f, 0.f);
#pragma unroll
        for (int j = 0; j < 5; ++j) a = dp_acc(a, e5b0[j], buf2, Bsh, 4);
        const float pf = fmaf(a.x, a.x, a.y * a.y) * fact0;   // |coeff|^2 * prod(mu!)
        f0 = fmaf(pf, w0a, f0);
        f1 = fmaf(pf, w1a, f1);
    }
    if (has_p1) {
        float2 a = make_float2(0.f, 0.f);
#pragma unroll
        for (int j = 0; j < 5; ++j) a = dp_acc(a, e5b1[j], buf2, Bsh, 4);
        const float pf = fmaf(a.x, a.x, a.y * a.y) * fact1;
        f0 = fmaf(pf, w0b, f0);
        f1 = fmaf(pf, w1b, f1);
    }
#pragma unroll
    for (int off = 32; off > 0; off >>= 1) {
        f0 += __shfl_xor(f0, off, 64);
        f1 += __shfl_xor(f1, off, 64);
    }
    if (lane == 0) { fred[wid][0] = f0; fred[wid][1] = f1; }
    __syncthreads();                                            // [8] partials
    if (tid < 2) {
        float a = bout[tid];
#pragma unroll
        for (int w = 0; w < 16; ++w) a += fred[w][tid];
        out[n * 2 + tid] = a;
    }
}

extern "C" void kernel_launch(void* const* d_in, const int* in_sizes, int n_in,
                              void* d_out, int out_size, void* d_ws, size_t ws_size,
                              hipStream_t stream) {
    const float* x     = (const float*)d_in[0];
    const float* Wd    = (const float*)d_in[1];
    const float* bd    = (const float*)d_in[2];
    const float* U1L   = (const float*)d_in[3];
    const float* U1R   = (const float*)d_in[4];
    const float* UfL   = (const float*)d_in[5];
    const float* UfR   = (const float*)d_in[6];
    const float* Wout  = (const float*)d_in[7];
    const float* bout  = (const float*)d_in[8];
    const float* mask1 = (const float*)d_in[9];
    const float* norm2 = (const float*)d_in[10];
    const int*   rows1 = (const int*)d_in[11];
    const int*   rows2 = (const int*)d_in[12];
    float* out = (float*)d_out;

    hipLaunchKernelGGL(k_fused, dim3(256), dim3(1024), 0, stream,
                       x, Wd, bd, U1L, U1R, UfL, UfR, Wout, bout,
                       mask1, norm2, rows1, rows2, out);
}

// Round 10
// 12.839 us; speedup vs baseline: 1.2712x; 1.2712x over previous
//
#include <hip/hip_runtime.h>
#include <hip/hip_bf16.h>

// Fully-fused quantum photonic classifier via polynomial-coefficient DP.
// perm(B[rows mu]) / prod(mu!) = coeff of x^mu in prod_c (sum_m x_m B[m][c]).
// One block per sample (256 x 1024). DP: Bsh -> st3(220, direct 3x3 permanent)
// -> st4(715) -> st5(252 / 2002).
// R10 vs R8: ALL combinatorial index tables (DP edges, 1/nu!, prod(mu!),
// mode bitmasks) are constexpr-generated at COMPILE time into device .rodata
// (rows1/rows2/mask1/norm2 are deterministic combinatorics) -- removes the
// ~400-op/thread runtime edge-build burst and those global loads entirely.
// Stage-2 is fused into a direct 3x3-permanent stage-3 (saves 2 barriers).
// R9's wave-0 serialization regressed and is reverted.

__device__ __forceinline__ float2 cxmul(float2 a, float2 b) {
    float2 r;
    r.x = fmaf(a.x, b.x, -(a.y * b.y));
    r.y = fmaf(a.x, b.y, a.y * b.x);
    return r;
}
__device__ __forceinline__ float2 cadd(float2 a, float2 b) {
    return make_float2(a.x + b.x, a.y + b.y);
}

// ---- compile-time combinatorics ------------------------------------------
struct BTab { int v[16][7]; };
constexpr BTab make_btab() {
    BTab t{};
    for (int n = 0; n < 16; ++n)
        for (int k = 0; k < 7; ++k) {
            if (k == 0) t.v[n][k] = 1;
            else if (n == 0) t.v[n][k] = 0;
            else t.v[n][k] = t.v[n - 1][k - 1] + t.v[n - 1][k];
        }
    return t;
}
constexpr BTab BT = make_btab();

// colex rank of ascending multiset: R = sum_i C(m_i + i, i+1)
constexpr int rank3c(int a, int b, int c) {
    return BT.v[a][1] + BT.v[b + 1][2] + BT.v[c + 2][3];
}
constexpr int rank4c(int a, int b, int c, int d) {
    return BT.v[a][1] + BT.v[b + 1][2] + BT.v[c + 2][3] + BT.v[d + 3][4];
}

struct T3 { unsigned pm[220]; float inv[220]; };
constexpr T3 gen3() {
    T3 t{};
    for (int a = 0; a <= 9; ++a)
        for (int b = a; b <= 9; ++b)
            for (int c = b; c <= 9; ++c) {
                const int R = rank3c(a, b, c);
                t.pm[R] = (unsigned)a | ((unsigned)b << 4) | ((unsigned)c << 8);
                int f = 1;
                if (a == b && b == c) f = 6;
                else if (a == b || b == c) f = 2;
                t.inv[R] = 1.0f / (float)f;
            }
    return t;
}
__device__ constexpr T3 T3T = gen3();

struct T4 { unsigned e[715][4]; };
constexpr T4 gen4() {
    T4 t{};
    for (int a = 0; a <= 9; ++a)
     for (int b = a; b <= 9; ++b)
      for (int c = b; c <= 9; ++c)
       for (int d = c; d <= 9; ++d) {
           const int R = rank4c(a, b, c, d);
           const int m[4] = {a, b, c, d};
           for (int j = 0; j < 4; ++j) {
               if (j > 0 && m[j] == m[j - 1]) { t.e[R][j] = 0u; continue; }
               int p[3]; int q = 0;
               for (int i = 0; i < 4; ++i) if (i != j) p[q++] = m[i];
               t.e[R][j] = ((unsigned)rank3c(p[0], p[1], p[2]) << 4)
                         | (unsigned)m[j] | 0x80000000u;
           }
       }
    return t;
}
__device__ constexpr T4 T4T = gen4();

struct T5A { unsigned e[252][5]; unsigned cm[252]; };   // lex order = itertools.combinations
constexpr T5A gen5a() {
    T5A t{};
    int p = 0;
    for (int a = 0; a <= 9; ++a)
     for (int b = a + 1; b <= 9; ++b)
      for (int c = b + 1; c <= 9; ++c)
       for (int d = c + 1; d <= 9; ++d)
        for (int g = d + 1; g <= 9; ++g) {
            const int m[5] = {a, b, c, d, g};
            for (int j = 0; j < 5; ++j) {
                int q4[4]; int q = 0;
                for (int i = 0; i < 5; ++i) if (i != j) q4[q++] = m[i];
                t.e[p][j] = ((unsigned)rank4c(q4[0], q4[1], q4[2], q4[3]) << 4)
                          | (unsigned)m[j] | 0x80000000u;
            }
            t.cm[p] = (1u << a) | (1u << b) | (1u << c) | (1u << d) | (1u << g);
            ++p;
        }
    return t;
}
__device__ constexpr T5A T5AT = gen5a();

struct T5B { unsigned e[2002][5]; float fact[2002]; };  // lex order = itertools.cwr
constexpr T5B gen5b() {
    T5B t{};
    int p = 0;
    for (int a = 0; a <= 9; ++a)
     for (int b = a; b <= 9; ++b)
      for (int c = b; c <= 9; ++c)
       for (int d = c; d <= 9; ++d)
        for (int g = d; g <= 9; ++g) {
            const int m[5] = {a, b, c, d, g};
            for (int j = 0; j < 5; ++j) {
                if (j > 0 && m[j] == m[j - 1]) { t.e[p][j] = 0u; continue; }
                int q4[4]; int q = 0;
                for (int i = 0; i < 5; ++i) if (i != j) q4[q++] = m[i];
                t.e[p][j] = ((unsigned)rank4c(q4[0], q4[1], q4[2], q4[3]) << 4)
                          | (unsigned)m[j] | 0x80000000u;
            }
            int f = 1, cnt = 1;
            for (int i = 1; i < 5; ++i) { cnt = (m[i] == m[i - 1]) ? cnt + 1 : 1; f *= cnt; }
            t.fact[p] = (float)f;
            ++p;
        }
    return t;
}
__device__ constexpr T5B T5BT = gen5b();

// acc += B[mode][col] * parent_coeff   (complex, 4 fma)
__device__ __forceinline__ float2 dp_acc(float2 acc, unsigned e, const float2* pbuf,
                                         const float2* B, int col) {
    if (e & 0x80000000u) {
        float2 p = pbuf[(e >> 4) & 0x3FFu];
        float2 b = B[(e & 15u) * 5 + col];
        acc.x = fmaf(b.x, p.x, acc.x);
        acc.x = fmaf(-b.y, p.y, acc.x);
        acc.y = fmaf(b.x, p.y, acc.y);
        acc.y = fmaf(b.y, p.x, acc.y);
    }
    return acc;
}

__global__ __launch_bounds__(1024) void k_fused(
    const float* __restrict__ x, const float* __restrict__ Wd, const float* __restrict__ bd,
    const float* __restrict__ U1L, const float* __restrict__ U1R,
    const float* __restrict__ UfL, const float* __restrict__ UfR,
    const float* __restrict__ Wout, const float* __restrict__ bout,
    float* __restrict__ out)
{
    const int n    = blockIdx.x;
    const int tid  = threadIdx.x;
    const int lane = tid & 63;
    const int wid  = tid >> 6;   // 16 waves

    __shared__ float2 Bsh[50];        // circuit matrix (10 modes x 5 cols)
    __shared__ float2 st3[220];
    __shared__ float2 st4[715];
    __shared__ float  p1s[252];
    __shared__ float2 Dsh[10];
    __shared__ float  fred[16][2];

    // ---- hoist all rodata-table + Wout loads into registers -------------
    unsigned pm3 = 0u; float inv3 = 0.f;
    if (tid < 220) { pm3 = T3T.pm[tid]; inv3 = T3T.inv[tid]; }
    unsigned e4[4] = {0u, 0u, 0u, 0u};
    if (tid < 715) {
#pragma unroll
        for (int j = 0; j < 4; ++j) e4[j] = T4T.e[tid][j];
    }
    unsigned e5a[5] = {0u, 0u, 0u, 0u, 0u};
    if (tid < 252) {
#pragma unroll
        for (int j = 0; j < 5; ++j) e5a[j] = T5AT.e[tid][j];
    }
    unsigned e5b0[5];
#pragma unroll
    for (int j = 0; j < 5; ++j) e5b0[j] = T5BT.e[tid][j];
    const bool has_p1 = (tid + 1024) < 2002;
    unsigned e5b1[5] = {0u, 0u, 0u, 0u, 0u};
    if (has_p1) {
#pragma unroll
        for (int j = 0; j < 5; ++j) e5b1[j] = T5BT.e[tid + 1024][j];
    }
    const float fact0 = T5BT.fact[tid];
    const float fact1 = has_p1 ? T5BT.fact[tid + 1024] : 0.f;
    const float w0a = Wout[tid];
    const float w1a = Wout[2002 + tid];
    const float w0b = has_p1 ? Wout[tid + 1024] : 0.f;
    const float w1b = has_p1 ? Wout[2002 + tid + 1024] : 0.f;
    unsigned cmw[4] = {0u, 0u, 0u, 0u};
    if (wid < 10) {
#pragma unroll
        for (int t = 0; t < 4; ++t) {
            const int p = lane + t * 64;
            cmw[t] = (p < 252) ? T5AT.cm[p] : 0u;
        }
    }

    // ---- phase 1: wave j computes h[j] = x[n]·Wd[j,:] + bd[j] -> D1 -----
    if (wid < 10) {
        const float* xr = x + n * 784;
        const float* wr = Wd + wid * 784;
        float s0 = 0.f, s1 = 0.f, s2 = 0.f, s3 = 0.f;
#pragma unroll
        for (int t = 0; t < 12; t += 4) {
            s0 = fmaf(xr[lane + t * 64],       wr[lane + t * 64],       s0);
            s1 = fmaf(xr[lane + (t + 1) * 64], wr[lane + (t + 1) * 64], s1);
            s2 = fmaf(xr[lane + (t + 2) * 64], wr[lane + (t + 2) * 64], s2);
            s3 = fmaf(xr[lane + (t + 3) * 64], wr[lane + (t + 3) * 64], s3);
        }
        if (lane < 16) s0 = fmaf(xr[lane + 768], wr[lane + 768], s0);
        float s = (s0 + s1) + (s2 + s3);
#pragma unroll
        for (int off = 32; off > 0; off >>= 1) s += __shfl_xor(s, off, 64);
        if (lane == 0) {
            float h = s + bd[wid];
            float sn, cs;
            __sincosf(h * 0.31830988618379067154f, &sn, &cs);   // h / pi
            Dsh[wid] = make_float2(cs, sn);
        }
    }
    __syncthreads();                                            // [1] Dsh

    // ---- B1 = U1L diag(D1) U1R[:, even] ---------------------------------
    if (tid < 50) {
        const int i = tid / 5, k = 2 * (tid % 5);
        float2 a = make_float2(0.f, 0.f);
#pragma unroll
        for (int j = 0; j < 10; ++j) {
            float2 ul = make_float2(U1L[(i * 10 + j) * 2], U1L[(i * 10 + j) * 2 + 1]);
            float2 ur = make_float2(U1R[(j * 10 + k) * 2], U1R[(j * 10 + k) * 2 + 1]);
            float2 t = cxmul(cxmul(ul, Dsh[j]), ur);
            a.x += t.x; a.y += t.y;
        }
        Bsh[tid] = a;
    }
    __syncthreads();                                            // [2] B1

    // ---- st3: direct 3x3 permanent / nu! over cols 0,1,2 ----------------
    if (tid < 220) {
        const int a = pm3 & 15u, b = (pm3 >> 4) & 15u, c = (pm3 >> 8) & 15u;
        const float2 A0 = Bsh[a * 5 + 0], A1 = Bsh[a * 5 + 1], A2 = Bsh[a * 5 + 2];
        const float2 B0 = Bsh[b * 5 + 0], B1 = Bsh[b * 5 + 1], B2 = Bsh[b * 5 + 2];
        const float2 C0 = Bsh[c * 5 + 0], C1 = Bsh[c * 5 + 1], C2 = Bsh[c * 5 + 2];
        float2 r = cxmul(A0, cadd(cxmul(B1, C2), cxmul(C1, B2)));
        r = cadd(r, cxmul(B0, cadd(cxmul(A1, C2), cxmul(C1, A2))));
        r = cadd(r, cxmul(C0, cadd(cxmul(A1, B2), cxmul(B1, A2))));
        st3[tid] = make_float2(r.x * inv3, r.y * inv3);
    }
    __syncthreads();                                            // [3] st3
    if (tid < 715) {
        float2 a = make_float2(0.f, 0.f);
#pragma unroll
        for (int j = 0; j < 4; ++j) a = dp_acc(a, e4[j], st3, Bsh, 3);
        st4[tid] = a;
    }
    __syncthreads();                                            // [4] st4
    if (tid < 252) {
        float2 a = make_float2(0.f, 0.f);
#pragma unroll
        for (int j = 0; j < 5; ++j) a = dp_acc(a, e5a[j], st4, Bsh, 4);
        p1s[tid] = fmaf(a.x, a.x, a.y * a.y);   // squarefree: prod(mu!) = 1
    }
    __syncthreads();                                            // [5] p1

    // ---- e1: wave j computes (p1·mask[:,j]) / sum(p1) -> D2 -------------
    if (wid < 10) {
        float sm = 0.f, st = 0.f;
#pragma unroll
        for (int t = 0; t < 4; ++t) {
            const int p = lane + t * 64;
            if (p < 252) {
                const float pv = p1s[p];
                sm = fmaf(pv, (float)((cmw[t] >> wid) & 1u), sm);
                st += pv;
            }
        }
#pragma unroll
        for (int off = 32; off > 0; off >>= 1) {
            sm += __shfl_xor(sm, off, 64);
            st += __shfl_xor(st, off, 64);
        }
        if (lane == 0) {
            float e = sm / st;
            float sn, cs;
            __sincosf(e, &sn, &cs);
            Dsh[wid] = make_float2(cs, sn);
        }
    }
    __syncthreads();                                            // [6] D2

    // ---- B2 = UfL diag(D2) UfR[:, even] ---------------------------------
    if (tid < 50) {
        const int i = tid / 5, k = 2 * (tid % 5);
        float2 a = make_float2(0.f, 0.f);
#pragma unroll
        for (int j = 0; j < 10; ++j) {
            float2 ul = make_float2(UfL[(i * 10 + j) * 2], UfL[(i * 10 + j) * 2 + 1]);
            float2 ur = make_float2(UfR[(j * 10 + k) * 2], UfR[(j * 10 + k) * 2 + 1]);
            float2 t = cxmul(cxmul(ul, Dsh[j]), ur);
            a.x += t.x; a.y += t.y;
        }
        Bsh[tid] = a;
    }
    __syncthreads();                                            // [7] B2

    if (tid < 220) {
        const int a = pm3 & 15u, b = (pm3 >> 4) & 15u, c = (pm3 >> 8) & 15u;
        const float2 A0 = Bsh[a * 5 + 0], A1 = Bsh[a * 5 + 1], A2 = Bsh[a * 5 + 2];
        const float2 B0 = Bsh[b * 5 + 0], B1 = Bsh[b * 5 + 1], B2 = Bsh[b * 5 + 2];
        const float2 C0 = Bsh[c * 5 + 0], C1 = Bsh[c * 5 + 1], C2 = Bsh[c * 5 + 2];
        float2 r = cxmul(A0, cadd(cxmul(B1, C2), cxmul(C1, B2)));
        r = cadd(r, cxmul(B0, cadd(cxmul(A1, C2), cxmul(C1, A2))));
        r = cadd(r, cxmul(C0, cadd(cxmul(A1, B2), cxmul(B1, A2))));
        st3[tid] = make_float2(r.x * inv3, r.y * inv3);
    }
    __syncthreads();                                            // [8] st3
    if (tid < 715) {
        float2 a = make_float2(0.f, 0.f);
#pragma unroll
        for (int j = 0; j < 4; ++j) a = dp_acc(a, e4[j], st3, Bsh, 3);
        st4[tid] = a;
    }
    __syncthreads();                                            // [9] st4

    // ---- st5 circuit-2 + W_out dot --------------------------------------
    float f0 = 0.f, f1 = 0.f;
    {
        float2 a = make_float2(0.f, 0.f);
#pragma unroll
        for (int j = 0; j < 5; ++j) a = dp_acc(a, e5b0[j], st4, Bsh, 4);
        const float pf = fmaf(a.x, a.x, a.y * a.y) * fact0;   // |coeff|^2 * prod(mu!)
        f0 = fmaf(pf, w0a, f0);
        f1 = fmaf(pf, w1a, f1);
    }
    if (has_p1) {
        float2 a = make_float2(0.f, 0.f);
#pragma unroll
        for (int j = 0; j < 5; ++j) a = dp_acc(a, e5b1[j], st4, Bsh, 4);
        const float pf = fmaf(a.x, a.x, a.y * a.y) * fact1;
        f0 = fmaf(pf, w0b, f0);
        f1 = fmaf(pf, w1b, f1);
    }
#pragma unroll
    for (int off = 32; off > 0; off >>= 1) {
        f0 += __shfl_xor(f0, off, 64);
        f1 += __shfl_xor(f1, off, 64);
    }
    if (lane == 0) { fred[wid][0] = f0; fred[wid][1] = f1; }
    __syncthreads();                                            // [10] partials
    if (tid < 2) {
        float a = bout[tid];
#pragma unroll
        for (int w = 0; w < 16; ++w) a += fred[w][tid];
        out[n * 2 + tid] = a;
    }
}

extern "C" void kernel_launch(void* const* d_in, const int* in_sizes, int n_in,
                              void* d_out, int out_size, void* d_ws, size_t ws_size,
                              hipStream_t stream) {
    const float* x     = (const float*)d_in[0];
    const float* Wd    = (const float*)d_in[1];
    const float* bd    = (const float*)d_in[2];
    const float* U1L   = (const float*)d_in[3];
    const float* U1R   = (const float*)d_in[4];
    const float* UfL   = (const float*)d_in[5];
    const float* UfR   = (const float*)d_in[6];
    const float* Wout  = (const float*)d_in[7];
    const float* bout  = (const float*)d_in[8];
    float* out = (float*)d_out;

    hipLaunchKernelGGL(k_fused, dim3(256), dim3(1024), 0, stream,
                       x, Wd, bd, U1L, U1R, UfL, UfR, Wout, bout, out);
}

// Round 11
// 12.522 us; speedup vs baseline: 1.3034x; 1.0253x over previous
//
#include <hip/hip_runtime.h>
#include <hip/hip_bf16.h>

// Fully-fused quantum photonic classifier via polynomial-coefficient DP.
// perm(B[rows mu]) / prod(mu!) = coeff of x^mu in prod_c (sum_m x_m B[m][c]).
// One block per sample (256 x 1024). DP: Bsh -> st3(220, direct 3x3 permanent)
// -> st4(715) -> st5(252 / 2002). All combinatorial tables constexpr .rodata.
// R11 vs R10: (1) U1L/U1R/UfL/UfR hoisted to registers BEFORE barrier[1]
// (removes L2 latency from the B1/B2 chain links; all later barriers have
// zero outstanding vmem), (2) B-build pair-split (threads 0-99, shfl_xor(1)
// combine) halving its dependent-fma chain, (3) final reduce = wave-0
// 16-lane shuffle tree instead of 2x16 serial LDS adds.

__device__ __forceinline__ float2 cxmul(float2 a, float2 b) {
    float2 r;
    r.x = fmaf(a.x, b.x, -(a.y * b.y));
    r.y = fmaf(a.x, b.y, a.y * b.x);
    return r;
}
__device__ __forceinline__ float2 cadd(float2 a, float2 b) {
    return make_float2(a.x + b.x, a.y + b.y);
}

// ---- compile-time combinatorics ------------------------------------------
struct BTab { int v[16][7]; };
constexpr BTab make_btab() {
    BTab t{};
    for (int n = 0; n < 16; ++n)
        for (int k = 0; k < 7; ++k) {
            if (k == 0) t.v[n][k] = 1;
            else if (n == 0) t.v[n][k] = 0;
            else t.v[n][k] = t.v[n - 1][k - 1] + t.v[n - 1][k];
        }
    return t;
}
constexpr BTab BT = make_btab();

constexpr int rank3c(int a, int b, int c) {
    return BT.v[a][1] + BT.v[b + 1][2] + BT.v[c + 2][3];
}
constexpr int rank4c(int a, int b, int c, int d) {
    return BT.v[a][1] + BT.v[b + 1][2] + BT.v[c + 2][3] + BT.v[d + 3][4];
}

struct T3 { unsigned pm[220]; float inv[220]; };
constexpr T3 gen3() {
    T3 t{};
    for (int a = 0; a <= 9; ++a)
        for (int b = a; b <= 9; ++b)
            for (int c = b; c <= 9; ++c) {
                const int R = rank3c(a, b, c);
                t.pm[R] = (unsigned)a | ((unsigned)b << 4) | ((unsigned)c << 8);
                int f = 1;
                if (a == b && b == c) f = 6;
                else if (a == b || b == c) f = 2;
                t.inv[R] = 1.0f / (float)f;
            }
    return t;
}
__device__ constexpr T3 T3T = gen3();

struct T4 { unsigned e[715][4]; };
constexpr T4 gen4() {
    T4 t{};
    for (int a = 0; a <= 9; ++a)
     for (int b = a; b <= 9; ++b)
      for (int c = b; c <= 9; ++c)
       for (int d = c; d <= 9; ++d) {
           const int R = rank4c(a, b, c, d);
           const int m[4] = {a, b, c, d};
           for (int j = 0; j < 4; ++j) {
               if (j > 0 && m[j] == m[j - 1]) { t.e[R][j] = 0u; continue; }
               int p[3]; int q = 0;
               for (int i = 0; i < 4; ++i) if (i != j) p[q++] = m[i];
               t.e[R][j] = ((unsigned)rank3c(p[0], p[1], p[2]) << 4)
                         | (unsigned)m[j] | 0x80000000u;
           }
       }
    return t;
}
__device__ constexpr T4 T4T = gen4();

struct T5A { unsigned e[252][5]; unsigned cm[252]; };   // lex = itertools.combinations
constexpr T5A gen5a() {
    T5A t{};
    int p = 0;
    for (int a = 0; a <= 9; ++a)
     for (int b = a + 1; b <= 9; ++b)
      for (int c = b + 1; c <= 9; ++c)
       for (int d = c + 1; d <= 9; ++d)
        for (int g = d + 1; g <= 9; ++g) {
            const int m[5] = {a, b, c, d, g};
            for (int j = 0; j < 5; ++j) {
                int q4[4]; int q = 0;
                for (int i = 0; i < 5; ++i) if (i != j) q4[q++] = m[i];
                t.e[p][j] = ((unsigned)rank4c(q4[0], q4[1], q4[2], q4[3]) << 4)
                          | (unsigned)m[j] | 0x80000000u;
            }
            t.cm[p] = (1u << a) | (1u << b) | (1u << c) | (1u << d) | (1u << g);
            ++p;
        }
    return t;
}
__device__ constexpr T5A T5AT = gen5a();

struct T5B { unsigned e[2002][5]; float fact[2002]; };  // lex = itertools.cwr
constexpr T5B gen5b() {
    T5B t{};
    int p = 0;
    for (int a = 0; a <= 9; ++a)
     for (int b = a; b <= 9; ++b)
      for (int c = b; c <= 9; ++c)
       for (int d = c; d <= 9; ++d)
        for (int g = d; g <= 9; ++g) {
            const int m[5] = {a, b, c, d, g};
            for (int j = 0; j < 5; ++j) {
                if (j > 0 && m[j] == m[j - 1]) { t.e[p][j] = 0u; continue; }
                int q4[4]; int q = 0;
                for (int i = 0; i < 5; ++i) if (i != j) q4[q++] = m[i];
                t.e[p][j] = ((unsigned)rank4c(q4[0], q4[1], q4[2], q4[3]) << 4)
                          | (unsigned)m[j] | 0x80000000u;
            }
            int f = 1, cnt = 1;
            for (int i = 1; i < 5; ++i) { cnt = (m[i] == m[i - 1]) ? cnt + 1 : 1; f *= cnt; }
            t.fact[p] = (float)f;
            ++p;
        }
    return t;
}
__device__ constexpr T5B T5BT = gen5b();

// acc += B[mode][col] * parent_coeff   (complex, 4 fma)
__device__ __forceinline__ float2 dp_acc(float2 acc, unsigned e, const float2* pbuf,
                                         const float2* B, int col) {
    if (e & 0x80000000u) {
        float2 p = pbuf[(e >> 4) & 0x3FFu];
        float2 b = B[(e & 15u) * 5 + col];
        acc.x = fmaf(b.x, p.x, acc.x);
        acc.x = fmaf(-b.y, p.y, acc.x);
        acc.y = fmaf(b.x, p.y, acc.y);
        acc.y = fmaf(b.y, p.x, acc.y);
    }
    return acc;
}

__global__ __launch_bounds__(1024) void k_fused(
    const float* __restrict__ x, const float* __restrict__ Wd, const float* __restrict__ bd,
    const float* __restrict__ U1L, const float* __restrict__ U1R,
    const float* __restrict__ UfL, const float* __restrict__ UfR,
    const float* __restrict__ Wout, const float* __restrict__ bout,
    float* __restrict__ out)
{
    const int n    = blockIdx.x;
    const int tid  = threadIdx.x;
    const int lane = tid & 63;
    const int wid  = tid >> 6;   // 16 waves

    __shared__ float2 Bsh[50];        // circuit matrix (10 modes x 5 cols)
    __shared__ float2 st3[220];
    __shared__ float2 st4[715];
    __shared__ float  p1s[252];
    __shared__ float2 Dsh[10];
    __shared__ float  fred[16][2];

    // ---- hoist rodata tables + Wout + U matrices into registers ---------
    unsigned pm3 = 0u; float inv3 = 0.f;
    if (tid < 220) { pm3 = T3T.pm[tid]; inv3 = T3T.inv[tid]; }
    unsigned e4[4] = {0u, 0u, 0u, 0u};
    if (tid < 715) {
#pragma unroll
        for (int j = 0; j < 4; ++j) e4[j] = T4T.e[tid][j];
    }
    unsigned e5a[5] = {0u, 0u, 0u, 0u, 0u};
    if (tid < 252) {
#pragma unroll
        for (int j = 0; j < 5; ++j) e5a[j] = T5AT.e[tid][j];
    }
    unsigned e5b0[5];
#pragma unroll
    for (int j = 0; j < 5; ++j) e5b0[j] = T5BT.e[tid][j];
    const bool has_p1 = (tid + 1024) < 2002;
    unsigned e5b1[5] = {0u, 0u, 0u, 0u, 0u};
    if (has_p1) {
#pragma unroll
        for (int j = 0; j < 5; ++j) e5b1[j] = T5BT.e[tid + 1024][j];
    }
    const float fact0 = T5BT.fact[tid];
    const float fact1 = has_p1 ? T5BT.fact[tid + 1024] : 0.f;
    const float w0a = Wout[tid];
    const float w1a = Wout[2002 + tid];
    const float w0b = has_p1 ? Wout[tid + 1024] : 0.f;
    const float w1b = has_p1 ? Wout[2002 + tid + 1024] : 0.f;
    unsigned cmw[4] = {0u, 0u, 0u, 0u};
    if (wid < 10) {
#pragma unroll
        for (int t = 0; t < 4; ++t) {
            const int p = lane + t * 64;
            cmw[t] = (p < 252) ? T5AT.cm[p] : 0u;
        }
    }
    // B-build operand hoist: pair (2q, 2q+1) handles entry q; parity picks
    // the j-half. u*[t] = U?L[i][jb+t], U?R[jb+t][k] (complex).
    const int q   = tid >> 1;
    const int par = tid & 1;
    const int bi  = q / 5;            // output row i (valid for q < 50)
    const int bk  = 2 * (q % 5);      // input column k
    const int jb  = par * 5;
    float2 u1l[5], u1r[5], ufl[5], ufr[5];
    if (tid < 100) {
#pragma unroll
        for (int t = 0; t < 5; ++t) {
            const int j = jb + t;
            u1l[t] = make_float2(U1L[(bi * 10 + j) * 2], U1L[(bi * 10 + j) * 2 + 1]);
            u1r[t] = make_float2(U1R[(j * 10 + bk) * 2], U1R[(j * 10 + bk) * 2 + 1]);
            ufl[t] = make_float2(UfL[(bi * 10 + j) * 2], UfL[(bi * 10 + j) * 2 + 1]);
            ufr[t] = make_float2(UfR[(j * 10 + bk) * 2], UfR[(j * 10 + bk) * 2 + 1]);
        }
    }

    // ---- phase 1: wave j computes h[j] = x[n]·Wd[j,:] + bd[j] -> D1 -----
    if (wid < 10) {
        const float* xr = x + n * 784;
        const float* wr = Wd + wid * 784;
        float s0 = 0.f, s1 = 0.f, s2 = 0.f, s3 = 0.f;
#pragma unroll
        for (int t = 0; t < 12; t += 4) {
            s0 = fmaf(xr[lane + t * 64],       wr[lane + t * 64],       s0);
            s1 = fmaf(xr[lane + (t + 1) * 64], wr[lane + (t + 1) * 64], s1);
            s2 = fmaf(xr[lane + (t + 2) * 64], wr[lane + (t + 2) * 64], s2);
            s3 = fmaf(xr[lane + (t + 3) * 64], wr[lane + (t + 3) * 64], s3);
        }
        if (lane < 16) s0 = fmaf(xr[lane + 768], wr[lane + 768], s0);
        float s = (s0 + s1) + (s2 + s3);
#pragma unroll
        for (int off = 32; off > 0; off >>= 1) s += __shfl_xor(s, off, 64);
        if (lane == 0) {
            float h = s + bd[wid];
            float sn, cs;
            __sincosf(h * 0.31830988618379067154f, &sn, &cs);   // h / pi
            Dsh[wid] = make_float2(cs, sn);
        }
    }
    __syncthreads();                                            // [1] Dsh

    // ---- B1: pair-split build (threads 0-99) ----------------------------
    if (tid < 100) {
        float2 a = make_float2(0.f, 0.f);
#pragma unroll
        for (int t = 0; t < 5; ++t) {
            float2 tt = cxmul(cxmul(u1l[t], Dsh[jb + t]), u1r[t]);
            a.x += tt.x; a.y += tt.y;
        }
        a.x += __shfl_xor(a.x, 1, 64);
        a.y += __shfl_xor(a.y, 1, 64);
        if (par == 0) Bsh[q] = a;
    }
    __syncthreads();                                            // [2] B1

    // ---- st3: direct 3x3 permanent / nu! over cols 0,1,2 ----------------
    if (tid < 220) {
        const int a = pm3 & 15u, b = (pm3 >> 4) & 15u, c = (pm3 >> 8) & 15u;
        const float2 A0 = Bsh[a * 5 + 0], A1 = Bsh[a * 5 + 1], A2 = Bsh[a * 5 + 2];
        const float2 B0 = Bsh[b * 5 + 0], B1 = Bsh[b * 5 + 1], B2 = Bsh[b * 5 + 2];
        const float2 C0 = Bsh[c * 5 + 0], C1 = Bsh[c * 5 + 1], C2 = Bsh[c * 5 + 2];
        float2 r = cxmul(A0, cadd(cxmul(B1, C2), cxmul(C1, B2)));
        r = cadd(r, cxmul(B0, cadd(cxmul(A1, C2), cxmul(C1, A2))));
        r = cadd(r, cxmul(C0, cadd(cxmul(A1, B2), cxmul(B1, A2))));
        st3[tid] = make_float2(r.x * inv3, r.y * inv3);
    }
    __syncthreads();                                            // [3] st3
    if (tid < 715) {
        float2 a = make_float2(0.f, 0.f);
#pragma unroll
        for (int j = 0; j < 4; ++j) a = dp_acc(a, e4[j], st3, Bsh, 3);
        st4[tid] = a;
    }
    __syncthreads();                                            // [4] st4
    if (tid < 252) {
        float2 a = make_float2(0.f, 0.f);
#pragma unroll
        for (int j = 0; j < 5; ++j) a = dp_acc(a, e5a[j], st4, Bsh, 4);
        p1s[tid] = fmaf(a.x, a.x, a.y * a.y);   // squarefree: prod(mu!) = 1
    }
    __syncthreads();                                            // [5] p1

    // ---- e1: wave j computes (p1·mask[:,j]) / sum(p1) -> D2 -------------
    if (wid < 10) {
        float sm = 0.f, st = 0.f;
#pragma unroll
        for (int t = 0; t < 4; ++t) {
            const int p = lane + t * 64;
            if (p < 252) {
                const float pv = p1s[p];
                sm = fmaf(pv, (float)((cmw[t] >> wid) & 1u), sm);
                st += pv;
            }
        }
#pragma unroll
        for (int off = 32; off > 0; off >>= 1) {
            sm += __shfl_xor(sm, off, 64);
            st += __shfl_xor(st, off, 64);
        }
        if (lane == 0) {
            float e = sm / st;
            float sn, cs;
            __sincosf(e, &sn, &cs);
            Dsh[wid] = make_float2(cs, sn);
        }
    }
    __syncthreads();                                            // [6] D2

    // ---- B2: pair-split build -------------------------------------------
    if (tid < 100) {
        float2 a = make_float2(0.f, 0.f);
#pragma unroll
        for (int t = 0; t < 5; ++t) {
            float2 tt = cxmul(cxmul(ufl[t], Dsh[jb + t]), ufr[t]);
            a.x += tt.x; a.y += tt.y;
        }
        a.x += __shfl_xor(a.x, 1, 64);
        a.y += __shfl_xor(a.y, 1, 64);
        if (par == 0) Bsh[q] = a;
    }
    __syncthreads();                                            // [7] B2

    if (tid < 220) {
        const int a = pm3 & 15u, b = (pm3 >> 4) & 15u, c = (pm3 >> 8) & 15u;
        const float2 A0 = Bsh[a * 5 + 0], A1 = Bsh[a * 5 + 1], A2 = Bsh[a * 5 + 2];
        const float2 B0 = Bsh[b * 5 + 0], B1 = Bsh[b * 5 + 1], B2 = Bsh[b * 5 + 2];
        const float2 C0 = Bsh[c * 5 + 0], C1 = Bsh[c * 5 + 1], C2 = Bsh[c * 5 + 2];
        float2 r = cxmul(A0, cadd(cxmul(B1, C2), cxmul(C1, B2)));
        r = cadd(r, cxmul(B0, cadd(cxmul(A1, C2), cxmul(C1, A2))));
        r = cadd(r, cxmul(C0, cadd(cxmul(A1, B2), cxmul(B1, A2))));
        st3[tid] = make_float2(r.x * inv3, r.y * inv3);
    }
    __syncthreads();                                            // [8] st3
    if (tid < 715) {
        float2 a = make_float2(0.f, 0.f);
#pragma unroll
        for (int j = 0; j < 4; ++j) a = dp_acc(a, e4[j], st3, Bsh, 3);
        st4[tid] = a;
    }
    __syncthreads();                                            // [9] st4

    // ---- st5 circuit-2 + W_out dot --------------------------------------
    float f0 = 0.f, f1 = 0.f;
    {
        float2 a = make_float2(0.f, 0.f);
#pragma unroll
        for (int j = 0; j < 5; ++j) a = dp_acc(a, e5b0[j], st4, Bsh, 4);
        const float pf = fmaf(a.x, a.x, a.y * a.y) * fact0;   // |coeff|^2 * prod(mu!)
        f0 = fmaf(pf, w0a, f0);
        f1 = fmaf(pf, w1a, f1);
    }
    if (has_p1) {
        float2 a = make_float2(0.f, 0.f);
#pragma unroll
        for (int j = 0; j < 5; ++j) a = dp_acc(a, e5b1[j], st4, Bsh, 4);
        const float pf = fmaf(a.x, a.x, a.y * a.y) * fact1;
        f0 = fmaf(pf, w0b, f0);
        f1 = fmaf(pf, w1b, f1);
    }
#pragma unroll
    for (int off = 32; off > 0; off >>= 1) {
        f0 += __shfl_xor(f0, off, 64);
        f1 += __shfl_xor(f1, off, 64);
    }
    if (lane == 0) { fred[wid][0] = f0; fred[wid][1] = f1; }
    __syncthreads();                                            // [10] partials
    if (tid < 16) {
        float a0 = fred[tid][0];
        float a1 = fred[tid][1];
#pragma unroll
        for (int off = 8; off > 0; off >>= 1) {
            a0 += __shfl_xor(a0, off, 64);
            a1 += __shfl_xor(a1, off, 64);
        }
        if (tid == 0) {
            out[n * 2 + 0] = a0 + bout[0];
            out[n * 2 + 1] = a1 + bout[1];
        }
    }
}

extern "C" void kernel_launch(void* const* d_in, const int* in_sizes, int n_in,
                              void* d_out, int out_size, void* d_ws, size_t ws_size,
                              hipStream_t stream) {
    const float* x     = (const float*)d_in[0];
    const float* Wd    = (const float*)d_in[1];
    const float* bd    = (const float*)d_in[2];
    const float* U1L   = (const float*)d_in[3];
    const float* U1R   = (const float*)d_in[4];
    const float* UfL   = (const float*)d_in[5];
    const float* UfR   = (const float*)d_in[6];
    const float* Wout  = (const float*)d_in[7];
    const float* bout  = (const float*)d_in[8];
    float* out = (float*)d_out;

    hipLaunchKernelGGL(k_fused, dim3(256), dim3(1024), 0, stream,
                       x, Wd, bd, U1L, U1R, UfL, UfR, Wout, bout, out);
}

// Round 12
// 12.448 us; speedup vs baseline: 1.3111x; 1.0059x over previous
//
#include <hip/hip_runtime.h>
#include <hip/hip_bf16.h>

// Fully-fused quantum photonic classifier via polynomial-coefficient DP.
// perm(B[rows mu]) / prod(mu!) = coeff of x^mu in prod_c (sum_m x_m B[m][c]).
// One block per sample (256 x 1024).
// R12 vs R11: st3 stage DELETED -- st4 is computed directly from Bsh as a
// 4x4 permanent (2|2-row Laplace: 6 column-splits of perm2*perm2) scaled by
// constexpr 1/nu!. Circuit-1 uses the squarefree subset DP (st4: 210 subset
// entries instead of 715 multiset ones). Chain: 10 -> 8 barriers, two fewer
// LDS round-trips. Bsh padded to [10][10] float2 (80B rows: 16B-aligned for
// b128 row loads, <=2-way bank aliasing).

__device__ __forceinline__ float2 cxmul(float2 a, float2 b) {
    float2 r;
    r.x = fmaf(a.x, b.x, -(a.y * b.y));
    r.y = fmaf(a.x, b.y, a.y * b.x);
    return r;
}
__device__ __forceinline__ float2 cadd(float2 a, float2 b) {
    return make_float2(a.x + b.x, a.y + b.y);
}

// ---- compile-time combinatorics ------------------------------------------
struct BTab { int v[16][7]; };
constexpr BTab make_btab() {
    BTab t{};
    for (int n = 0; n < 16; ++n)
        for (int k = 0; k < 7; ++k) {
            if (k == 0) t.v[n][k] = 1;
            else if (n == 0) t.v[n][k] = 0;
            else t.v[n][k] = t.v[n - 1][k - 1] + t.v[n - 1][k];
        }
    return t;
}
constexpr BTab BT = make_btab();

// multiset colex rank (ascending a<=b<=c<=d)
constexpr int rank4m(int a, int b, int c, int d) {
    return BT.v[a][1] + BT.v[b + 1][2] + BT.v[c + 2][3] + BT.v[d + 3][4];
}
// subset colex rank (ascending a<b<c<d)
constexpr int rank4s(int a, int b, int c, int d) {
    return BT.v[a][1] + BT.v[b][2] + BT.v[c][3] + BT.v[d][4];
}

// 210 squarefree 4-subsets: packed modes, colex-ranked
struct S4SQ { unsigned pm[210]; };
constexpr S4SQ gen4sq() {
    S4SQ t{};
    for (int a = 0; a <= 9; ++a)
     for (int b = a + 1; b <= 9; ++b)
      for (int c = b + 1; c <= 9; ++c)
       for (int d = c + 1; d <= 9; ++d)
           t.pm[rank4s(a, b, c, d)] =
               (unsigned)a | ((unsigned)b << 4) | ((unsigned)c << 8) | ((unsigned)d << 12);
    return t;
}
__device__ constexpr S4SQ S4SQT = gen4sq();

// 715 4-multisets: packed modes + 1/nu!, colex-ranked
struct S4MS { unsigned pm[715]; float inv[715]; };
constexpr S4MS gen4ms() {
    S4MS t{};
    for (int a = 0; a <= 9; ++a)
     for (int b = a; b <= 9; ++b)
      for (int c = b; c <= 9; ++c)
       for (int d = c; d <= 9; ++d) {
           const int R = rank4m(a, b, c, d);
           t.pm[R] = (unsigned)a | ((unsigned)b << 4) | ((unsigned)c << 8) | ((unsigned)d << 12);
           const int m[4] = {a, b, c, d};
           int f = 1, cnt = 1;
           for (int i = 1; i < 4; ++i) { cnt = (m[i] == m[i - 1]) ? cnt + 1 : 1; f *= cnt; }
           t.inv[R] = 1.0f / (float)f;
       }
    return t;
}
__device__ constexpr S4MS S4MST = gen4ms();

// circuit-1 final stage: 252 lex 5-subsets -> 5 edges into subset-ranked st4
struct S5A { unsigned e[252][5]; unsigned cm[252]; };
constexpr S5A gen5a() {
    S5A t{};
    int p = 0;
    for (int a = 0; a <= 9; ++a)
     for (int b = a + 1; b <= 9; ++b)
      for (int c = b + 1; c <= 9; ++c)
       for (int d = c + 1; d <= 9; ++d)
        for (int g = d + 1; g <= 9; ++g) {
            const int m[5] = {a, b, c, d, g};
            for (int j = 0; j < 5; ++j) {
                int q4[4]; int q = 0;
                for (int i = 0; i < 5; ++i) if (i != j) q4[q++] = m[i];
                t.e[p][j] = ((unsigned)rank4s(q4[0], q4[1], q4[2], q4[3]) << 4)
                          | (unsigned)m[j];
            }
            t.cm[p] = (1u << a) | (1u << b) | (1u << c) | (1u << d) | (1u << g);
            ++p;
        }
    return t;
}
__device__ constexpr S5A S5AT = gen5a();

// circuit-2 final stage: 2002 lex 5-multisets -> edges into multiset st4
struct T5B { unsigned e[2002][5]; float fact[2002]; };
constexpr T5B gen5b() {
    T5B t{};
    int p = 0;
    for (int a = 0; a <= 9; ++a)
     for (int b = a; b <= 9; ++b)
      for (int c = b; c <= 9; ++c)
       for (int d = c; d <= 9; ++d)
        for (int g = d; g <= 9; ++g) {
            const int m[5] = {a, b, c, d, g};
            for (int j = 0; j < 5; ++j) {
                if (j > 0 && m[j] == m[j - 1]) { t.e[p][j] = 0u; continue; }
                int q4[4]; int q = 0;
                for (int i = 0; i < 5; ++i) if (i != j) q4[q++] = m[i];
                t.e[p][j] = ((unsigned)rank4m(q4[0], q4[1], q4[2], q4[3]) << 4)
                          | (unsigned)m[j] | 0x80000000u;
            }
            int f = 1, cnt = 1;
            for (int i = 1; i < 5; ++i) { cnt = (m[i] == m[i - 1]) ? cnt + 1 : 1; f *= cnt; }
            t.fact[p] = (float)f;
            ++p;
        }
    return t;
}
__device__ constexpr T5B T5BT = gen5b();

// ---- 4x4 permanent, rows packed 4-bit in pk, cols 0..3 of Bsh[10][10] ----
__device__ __forceinline__ void ld_row(const float2* Bsh, int m, float2 (&R)[4]) {
    const float4* p = (const float4*)(Bsh + m * 10);    // 80B rows, 16B aligned
    const float4 lo = p[0];
    const float4 hi = p[1];
    R[0] = make_float2(lo.x, lo.y);
    R[1] = make_float2(lo.z, lo.w);
    R[2] = make_float2(hi.x, hi.y);
    R[3] = make_float2(hi.z, hi.w);
}
__device__ __forceinline__ float2 p22(const float2 (&A)[4], const float2 (&B)[4], int i, int j) {
    return cadd(cxmul(A[i], B[j]), cxmul(A[j], B[i]));
}
__device__ __forceinline__ float2 perm4f(const float2* Bsh, unsigned pk) {
    const int r0 = pk & 15u, r1 = (pk >> 4) & 15u, r2 = (pk >> 8) & 15u, r3 = (pk >> 12) & 15u;
    float2 A[4], B[4], C[4], D[4];
    ld_row(Bsh, r0, A); ld_row(Bsh, r1, B);
    ld_row(Bsh, r2, C); ld_row(Bsh, r3, D);
    // perm = sum over 6 column 2|2 splits of perm2(rows01)*perm2(rows23)
    float2 t01 = p22(A, B, 0, 1), t23 = p22(A, B, 2, 3);
    float2 t02 = p22(A, B, 0, 2), t13 = p22(A, B, 1, 3);
    float2 t03 = p22(A, B, 0, 3), t12 = p22(A, B, 1, 2);
    float2 u01 = p22(C, D, 0, 1), u23 = p22(C, D, 2, 3);
    float2 u02 = p22(C, D, 0, 2), u13 = p22(C, D, 1, 3);
    float2 u03 = p22(C, D, 0, 3), u12 = p22(C, D, 1, 2);
    float2 r = cxmul(t01, u23);
    r = cadd(r, cxmul(t02, u13));
    r = cadd(r, cxmul(t03, u12));
    r = cadd(r, cxmul(t12, u03));
    r = cadd(r, cxmul(t13, u02));
    r = cadd(r, cxmul(t23, u01));
    return r;
}

__global__ __launch_bounds__(1024) void k_fused(
    const float* __restrict__ x, const float* __restrict__ Wd, const float* __restrict__ bd,
    const float* __restrict__ U1L, const float* __restrict__ U1R,
    const float* __restrict__ UfL, const float* __restrict__ UfR,
    const float* __restrict__ Wout, const float* __restrict__ bout,
    float* __restrict__ out)
{
    const int n    = blockIdx.x;
    const int tid  = threadIdx.x;
    const int lane = tid & 63;
    const int wid  = tid >> 6;   // 16 waves

    __shared__ float2 Bsh[100];       // 10 rows x 10 (cols 0..4 used, padded)
    __shared__ float2 st4[715];
    __shared__ float  p1s[252];
    __shared__ float2 Dsh[10];
    __shared__ float  fred[16][2];

    // ---- hoist rodata tables + Wout + U matrices into registers ---------
    unsigned pm4sq = 0u;
    if (tid < 210) pm4sq = S4SQT.pm[tid];
    unsigned pm4ms = 0u; float inv4 = 0.f;
    if (tid < 715) { pm4ms = S4MST.pm[tid]; inv4 = S4MST.inv[tid]; }
    unsigned e5a[5] = {0u, 0u, 0u, 0u, 0u};
    if (tid < 252) {
#pragma unroll
        for (int j = 0; j < 5; ++j) e5a[j] = S5AT.e[tid][j];
    }
    unsigned e5b0[5];
#pragma unroll
    for (int j = 0; j < 5; ++j) e5b0[j] = T5BT.e[tid][j];
    const bool has_p1 = (tid + 1024) < 2002;
    unsigned e5b1[5] = {0u, 0u, 0u, 0u, 0u};
    if (has_p1) {
#pragma unroll
        for (int j = 0; j < 5; ++j) e5b1[j] = T5BT.e[tid + 1024][j];
    }
    const float fact0 = T5BT.fact[tid];
    const float fact1 = has_p1 ? T5BT.fact[tid + 1024] : 0.f;
    const float w0a = Wout[tid];
    const float w1a = Wout[2002 + tid];
    const float w0b = has_p1 ? Wout[tid + 1024] : 0.f;
    const float w1b = has_p1 ? Wout[2002 + tid + 1024] : 0.f;
    unsigned cmw[4] = {0u, 0u, 0u, 0u};
    if (wid < 10) {
#pragma unroll
        for (int t = 0; t < 4; ++t) {
            const int p = lane + t * 64;
            cmw[t] = (p < 252) ? S5AT.cm[p] : 0u;
        }
    }
    // B-build operand hoist: pair (2q, 2q+1) handles entry q; parity = j-half
    const int q   = tid >> 1;
    const int par = tid & 1;
    const int bi  = q / 5;            // output row i (valid for q < 50)
    const int bc  = q % 5;            // column c
    const int bk  = 2 * bc;           // input mode k = even columns
    const int jb  = par * 5;
    float2 u1l[5], u1r[5], ufl[5], ufr[5];
    if (tid < 100) {
#pragma unroll
        for (int t = 0; t < 5; ++t) {
            const int j = jb + t;
            u1l[t] = make_float2(U1L[(bi * 10 + j) * 2], U1L[(bi * 10 + j) * 2 + 1]);
            u1r[t] = make_float2(U1R[(j * 10 + bk) * 2], U1R[(j * 10 + bk) * 2 + 1]);
            ufl[t] = make_float2(UfL[(bi * 10 + j) * 2], UfL[(bi * 10 + j) * 2 + 1]);
            ufr[t] = make_float2(UfR[(j * 10 + bk) * 2], UfR[(j * 10 + bk) * 2 + 1]);
        }
    }

    // ---- phase 1: wave j computes h[j] = x[n]·Wd[j,:] + bd[j] -> D1 -----
    if (wid < 10) {
        const float* xr = x + n * 784;
        const float* wr = Wd + wid * 784;
        float s0 = 0.f, s1 = 0.f, s2 = 0.f, s3 = 0.f;
#pragma unroll
        for (int t = 0; t < 12; t += 4) {
            s0 = fmaf(xr[lane + t * 64],       wr[lane + t * 64],       s0);
            s1 = fmaf(xr[lane + (t + 1) * 64], wr[lane + (t + 1) * 64], s1);
            s2 = fmaf(xr[lane + (t + 2) * 64], wr[lane + (t + 2) * 64], s2);
            s3 = fmaf(xr[lane + (t + 3) * 64], wr[lane + (t + 3) * 64], s3);
        }
        if (lane < 16) s0 = fmaf(xr[lane + 768], wr[lane + 768], s0);
        float s = (s0 + s1) + (s2 + s3);
#pragma unroll
        for (int off = 32; off > 0; off >>= 1) s += __shfl_xor(s, off, 64);
        if (lane == 0) {
            float h = s + bd[wid];
            float sn, cs;
            __sincosf(h * 0.31830988618379067154f, &sn, &cs);   // h / pi
            Dsh[wid] = make_float2(cs, sn);
        }
    }
    __syncthreads();                                            // [1] Dsh

    // ---- B1: pair-split build (threads 0-99) ----------------------------
    if (tid < 100) {
        float2 a = make_float2(0.f, 0.f);
#pragma unroll
        for (int t = 0; t < 5; ++t) {
            float2 tt = cxmul(cxmul(u1l[t], Dsh[jb + t]), u1r[t]);
            a.x += tt.x; a.y += tt.y;
        }
        a.x += __shfl_xor(a.x, 1, 64);
        a.y += __shfl_xor(a.y, 1, 64);
        if (par == 0) Bsh[bi * 10 + bc] = a;
    }
    __syncthreads();                                            // [2] B1

    // ---- circuit-1 st4: direct 4x4 permanent of subsets (210) -----------
    if (tid < 210) st4[tid] = perm4f(Bsh, pm4sq);
    __syncthreads();                                            // [3] st4sq
    // ---- p1 = |c5|^2 for 252 squarefree 5-subsets ------------------------
    if (tid < 252) {
        float2 a = make_float2(0.f, 0.f);
#pragma unroll
        for (int j = 0; j < 5; ++j) {
            const unsigned e = e5a[j];
            const float2 p = st4[e >> 4];
            const float2 b = Bsh[(e & 15u) * 10 + 4];
            a.x = fmaf(b.x, p.x, a.x);
            a.x = fmaf(-b.y, p.y, a.x);
            a.y = fmaf(b.x, p.y, a.y);
            a.y = fmaf(b.y, p.x, a.y);
        }
        p1s[tid] = fmaf(a.x, a.x, a.y * a.y);
    }
    __syncthreads();                                            // [4] p1

    // ---- e1: wave j computes (p1·mask[:,j]) / sum(p1) -> D2 -------------
    if (wid < 10) {
        float sm = 0.f, st = 0.f;
#pragma unroll
        for (int t = 0; t < 4; ++t) {
            const int p = lane + t * 64;
            if (p < 252) {
                const float pv = p1s[p];
                sm = fmaf(pv, (float)((cmw[t] >> wid) & 1u), sm);
                st += pv;
            }
        }
#pragma unroll
        for (int off = 32; off > 0; off >>= 1) {
            sm += __shfl_xor(sm, off, 64);
            st += __shfl_xor(st, off, 64);
        }
        if (lane == 0) {
            float e = sm / st;
            float sn, cs;
            __sincosf(e, &sn, &cs);
            Dsh[wid] = make_float2(cs, sn);
        }
    }
    __syncthreads();                                            // [5] D2

    // ---- B2: pair-split build -------------------------------------------
    if (tid < 100) {
        float2 a = make_float2(0.f, 0.f);
#pragma unroll
        for (int t = 0; t < 5; ++t) {
            float2 tt = cxmul(cxmul(ufl[t], Dsh[jb + t]), ufr[t]);
            a.x += tt.x; a.y += tt.y;
        }
        a.x += __shfl_xor(a.x, 1, 64);
        a.y += __shfl_xor(a.y, 1, 64);
        if (par == 0) Bsh[bi * 10 + bc] = a;
    }
    __syncthreads();                                            // [6] B2

    // ---- circuit-2 st4: direct 4x4 permanent / nu! (715 multisets) ------
    if (tid < 715) {
        float2 r = perm4f(Bsh, pm4ms);
        st4[tid] = make_float2(r.x * inv4, r.y * inv4);
    }
    __syncthreads();                                            // [7] st4ms

    // ---- st5 circuit-2 + W_out dot --------------------------------------
    float f0 = 0.f, f1 = 0.f;
    {
        float2 a = make_float2(0.f, 0.f);
#pragma unroll
        for (int j = 0; j < 5; ++j) {
            const unsigned e = e5b0[j];
            if (e & 0x80000000u) {
                const float2 p = st4[(e >> 4) & 0x3FFu];
                const float2 b = Bsh[(e & 15u) * 10 + 4];
                a.x = fmaf(b.x, p.x, a.x);
                a.x = fmaf(-b.y, p.y, a.x);
                a.y = fmaf(b.x, p.y, a.y);
                a.y = fmaf(b.y, p.x, a.y);
            }
        }
        const float pf = fmaf(a.x, a.x, a.y * a.y) * fact0;   // |coeff|^2 * prod(mu!)
        f0 = fmaf(pf, w0a, f0);
        f1 = fmaf(pf, w1a, f1);
    }
    if (has_p1) {
        float2 a = make_float2(0.f, 0.f);
#pragma unroll
        for (int j = 0; j < 5; ++j) {
            const unsigned e = e5b1[j];
            if (e & 0x80000000u) {
                const float2 p = st4[(e >> 4) & 0x3FFu];
                const float2 b = Bsh[(e & 15u) * 10 + 4];
                a.x = fmaf(b.x, p.x, a.x);
                a.x = fmaf(-b.y, p.y, a.x);
                a.y = fmaf(b.x, p.y, a.y);
                a.y = fmaf(b.y, p.x, a.y);
            }
        }
        const float pf = fmaf(a.x, a.x, a.y * a.y) * fact1;
        f0 = fmaf(pf, w0b, f0);
        f1 = fmaf(pf, w1b, f1);
    }
#pragma unroll
    for (int off = 32; off > 0; off >>= 1) {
        f0 += __shfl_xor(f0, off, 64);
        f1 += __shfl_xor(f1, off, 64);
    }
    if (lane == 0) { fred[wid][0] = f0; fred[wid][1] = f1; }
    __syncthreads();                                            // [8] partials
    if (tid < 16) {
        float a0 = fred[tid][0];
        float a1 = fred[tid][1];
#pragma unroll
        for (int off = 8; off > 0; off >>= 1) {
            a0 += __shfl_xor(a0, off, 64);
            a1 += __shfl_xor(a1, off, 64);
        }
        if (tid == 0) {
            out[n * 2 + 0] = a0 + bout[0];
            out[n * 2 + 1] = a1 + bout[1];
        }
    }
}

extern "C" void kernel_launch(void* const* d_in, const int* in_sizes, int n_in,
                              void* d_out, int out_size, void* d_ws, size_t ws_size,
                              hipStream_t stream) {
    const float* x     = (const float*)d_in[0];
    const float* Wd    = (const float*)d_in[1];
    const float* bd    = (const float*)d_in[2];
    const float* U1L   = (const float*)d_in[3];
    const float* U1R   = (const float*)d_in[4];
    const float* UfL   = (const float*)d_in[5];
    const float* UfR   = (const float*)d_in[6];
    const float* Wout  = (const float*)d_in[7];
    const float* bout  = (const float*)d_in[8];
    float* out = (float*)d_out;

    hipLaunchKernelGGL(k_fused, dim3(256), dim3(1024), 0, stream,
                       x, Wd, bd, U1L, U1R, UfL, UfR, Wout, bout, out);
}